// Round 6
// baseline (90.930 us; speedup 1.0000x reference)
//
#include <hip/hip_runtime.h>
#include <math.h>

typedef __attribute__((ext_vector_type(8))) short short8;
typedef __attribute__((ext_vector_type(4))) float f32x4;

__device__ inline short f2bf(float f) {
    unsigned u = __float_as_uint(f);
    u += 0x7FFFu + ((u >> 16) & 1u);   // RNE to bf16
    return (short)(u >> 16);
}

// ------ Kernel 1: cast centers (f32->bf16) + chalf[k] = 0.5*sum(c^2) in f32 ------
__global__ __launch_bounds__(256) void cast_centers_kernel(const float* __restrict__ c,
                                                           short* __restrict__ cb,
                                                           float* __restrict__ chalf, int dim) {
    int k = blockIdx.x;
    int t = threadIdx.x;
    const float* row = c + (size_t)k * dim;
    short* orow = cb + (size_t)k * dim;
    float s = 0.f;
    for (int i = t * 4; i < dim; i += blockDim.x * 4) {
        float4 v = *(const float4*)(row + i);
        s += v.x * v.x + v.y * v.y + v.z * v.z + v.w * v.w;
        short4 o;
        o.x = f2bf(v.x); o.y = f2bf(v.y); o.z = f2bf(v.z); o.w = f2bf(v.w);
        *(short4*)(orow + i) = o;
    }
#pragma unroll
    for (int off = 32; off; off >>= 1) s += __shfl_xor(s, off);
    __shared__ float red[4];
    if ((t & 63) == 0) red[t >> 6] = s;
    __syncthreads();
    if (t == 0) chalf[k] = 0.5f * (red[0] + red[1] + red[2] + red[3]);
}

// ------------- Kernel 2: fused GEMM (64 x FULL-ROW 1024) + log-softmax epilogue -------------
// logits[b,k] = x_b . c_k - 0.5*||c_k||^2  (row-constant -0.5*||x||^2 cancels in log_softmax)
// out[b,k] = logits[b,k] - logsumexp_k(logits[b,:])
//
// Structure: A (x rows, 64x1024 bf16 = 128 KB) staged ONCE into LDS (read-only after one
// barrier). B (centers, L2-resident) streams straight into registers, double-buffered
// ping/pong, peeled tail. K-loop has ZERO barriers / ZERO LDS writes -> 8 independent
// waves/CU hide L2 latency under MFMA. Epilogue log-softmax fused (scratch past A region).
// A swizzle: 16B chunk c of row r stored at chunk c ^ (r&7)  -> 2-way max on reads (free).
#define SCR 131072

__global__ __launch_bounds__(512, 2) void fused_kernel(
    const float* __restrict__ x,     // [M][K] f32
    const short* __restrict__ cb,    // [N][K] bf16
    const float* __restrict__ chalf, // [N]
    float* __restrict__ out,         // [M][N]
    int M, int N, int K) {
    __shared__ char lds[131072 + 4608];
    const int t = threadIdx.x;
    const int l = t & 63, w = t >> 6, lr = l & 15, hi = l >> 4;
    const int brow = blockIdx.x * 64;

    // ---------- prologue: stage A (f32 -> bf16, swizzled) ----------
    {
        const int ar = t >> 3;                 // row 0..63
        const int ac = (t & 7) * 4;            // base f32 col
        const float* xrow = x + (size_t)(brow + ar) * K;
#pragma unroll
        for (int jb = 0; jb < 4; ++jb) {
            float4 f[8];
#pragma unroll
            for (int jj = 0; jj < 8; ++jj)
                f[jj] = *(const float4*)(xrow + ac + (jb * 8 + jj) * 32);
#pragma unroll
            for (int jj = 0; jj < 8; ++jj) {
                const int c0 = ac + (jb * 8 + jj) * 32;
                short4 v;
                v.x = f2bf(f[jj].x); v.y = f2bf(f[jj].y);
                v.z = f2bf(f[jj].z); v.w = f2bf(f[jj].w);
                *(short4*)(lds + ar * 2048 + (((c0 >> 3) ^ (ar & 7)) << 4) + (c0 & 4) * 2) = v;
            }
        }
    }
    __syncthreads();

    // ---------- barrier-free K-loop ----------
    const int aswz = lr & 7;
    const short* bbase = cb + (size_t)(w * 128 + lr) * 1024 + hi * 8;

    f32x4 acc[4][8];
#pragma unroll
    for (int m = 0; m < 4; ++m)
#pragma unroll
        for (int n = 0; n < 8; ++n)
#pragma unroll
            for (int q = 0; q < 4; ++q) acc[m][n][q] = 0.f;

#define LDB(dst, k) do { _Pragma("unroll")                                       \
    for (int n = 0; n < 8; ++n)                                                  \
        dst[n] = *(const short8*)(bbase + n * 16384 + (k) * 32); } while (0)

#define STEP(bset, k) do {                                                       \
    short8 afr[4];                                                               \
    _Pragma("unroll")                                                            \
    for (int m = 0; m < 4; ++m)                                                  \
        afr[m] = *(const short8*)(lds + (m * 16 + lr) * 2048 +                   \
                                  ((((k) * 4 + hi) ^ aswz) << 4));               \
    __builtin_amdgcn_s_setprio(1);                                               \
    _Pragma("unroll")                                                            \
    for (int m = 0; m < 4; ++m)                                                  \
        _Pragma("unroll")                                                        \
        for (int n = 0; n < 8; ++n)                                              \
            acc[m][n] = __builtin_amdgcn_mfma_f32_16x16x32_bf16(afr[m], bset[n], \
                                                                acc[m][n], 0, 0, 0); \
    __builtin_amdgcn_s_setprio(0); } while (0)

    short8 bE[8], bO[8];
    LDB(bE, 0);
    for (int k2 = 0; k2 < 15; ++k2) {
        LDB(bO, 2 * k2 + 1);
        STEP(bE, 2 * k2);
        LDB(bE, 2 * k2 + 2);
        STEP(bO, 2 * k2 + 1);
    }
    LDB(bO, 31);
    STEP(bE, 30);
    STEP(bO, 31);
#undef LDB
#undef STEP

    // ================= fused log-softmax epilogue =================
    // C/D frag layout: col = lane&15, row = (lane>>4)*4 + q.
    // Lane holds rows R = m*16 + hi*4 + q, cols w*128 + n*16 + lr.
    float ch[8];
#pragma unroll
    for (int n = 0; n < 8; ++n) ch[n] = chalf[w * 128 + n * 16 + lr];

    // pass 1: per-lane max over n, reduce over lr-lanes, cross-wave via LDS scratch
    float pm[4][4];
#pragma unroll
    for (int m = 0; m < 4; ++m)
#pragma unroll
        for (int q = 0; q < 4; ++q) {
            float v = acc[m][0][q] - ch[0];
#pragma unroll
            for (int n = 1; n < 8; ++n) v = fmaxf(v, acc[m][n][q] - ch[n]);
            pm[m][q] = v;
        }
#pragma unroll
    for (int d = 1; d <= 8; d <<= 1)
#pragma unroll
        for (int m = 0; m < 4; ++m)
#pragma unroll
            for (int q = 0; q < 4; ++q) pm[m][q] = fmaxf(pm[m][q], __shfl_xor(pm[m][q], d));
    if (lr == 0) {
#pragma unroll
        for (int m = 0; m < 4; ++m)
#pragma unroll
            for (int q = 0; q < 4; ++q)
                *(float*)(lds + SCR + (m * 16 + hi * 4 + q) * 32 + w * 4) = pm[m][q]; // wmax[R][w]
    }
    __syncthreads();
    if (t < 64) {
        float4 a = *(const float4*)(lds + SCR + t * 32);
        float4 b = *(const float4*)(lds + SCR + t * 32 + 16);
        float g = fmaxf(fmaxf(fmaxf(a.x, a.y), fmaxf(a.z, a.w)),
                        fmaxf(fmaxf(b.x, b.y), fmaxf(b.z, b.w)));
        *(float*)(lds + SCR + 4096 + t * 4) = g;                                      // gmax[R]
    }
    __syncthreads();

    // pass 2: sum of exp
    float ps[4][4];
#pragma unroll
    for (int m = 0; m < 4; ++m)
#pragma unroll
        for (int q = 0; q < 4; ++q) {
            const float g = *(const float*)(lds + SCR + 4096 + (m * 16 + hi * 4 + q) * 4);
            float s = 0.f;
#pragma unroll
            for (int n = 0; n < 8; ++n) s += __expf(acc[m][n][q] - ch[n] - g);
            ps[m][q] = s;
        }
#pragma unroll
    for (int d = 1; d <= 8; d <<= 1)
#pragma unroll
        for (int m = 0; m < 4; ++m)
#pragma unroll
            for (int q = 0; q < 4; ++q) ps[m][q] += __shfl_xor(ps[m][q], d);
    if (lr == 0) {
#pragma unroll
        for (int m = 0; m < 4; ++m)
#pragma unroll
            for (int q = 0; q < 4; ++q)
                *(float*)(lds + SCR + 2048 + (m * 16 + hi * 4 + q) * 32 + w * 4) = ps[m][q]; // wsum[R][w]
    }
    __syncthreads();
    if (t < 64) {
        float4 a = *(const float4*)(lds + SCR + 2048 + t * 32);
        float4 b = *(const float4*)(lds + SCR + 2048 + t * 32 + 16);
        float s = (a.x + a.y + a.z + a.w) + (b.x + b.y + b.z + b.w);
        *(float*)(lds + SCR + 4352 + t * 4) =
            *(const float*)(lds + SCR + 4096 + t * 4) + __logf(s);                    // lse[R]
    }
    __syncthreads();

    // write final output
#pragma unroll
    for (int m = 0; m < 4; ++m)
#pragma unroll
        for (int q = 0; q < 4; ++q) {
            const int R = m * 16 + hi * 4 + q;
            const float lse = *(const float*)(lds + SCR + 4352 + R * 4);
            float* orow = out + (size_t)(brow + R) * N + w * 128 + lr;
#pragma unroll
            for (int n = 0; n < 8; ++n)
                orow[n * 16] = acc[m][n][q] - ch[n] - lse;
        }
}

extern "C" void kernel_launch(void* const* d_in, const int* in_sizes, int n_in,
                              void* d_out, int out_size, void* d_ws, size_t ws_size,
                              hipStream_t stream) {
    const float* x = (const float*)d_in[0];
    const float* c = (const float*)d_in[1];
    float* out = (float*)d_out;

    int dim = (int)(sqrt((double)in_sizes[1]) + 0.5);   // 1024
    int batch = in_sizes[0] / dim;                      // 16384

    // workspace layout: [centers bf16][chalf f32]
    size_t cb_bytes = (size_t)dim * dim * 2;
    short* cb = (short*)d_ws;
    float* chalf = (float*)((char*)d_ws + cb_bytes);

    cast_centers_kernel<<<dim, 256, 0, stream>>>(c, cb, chalf, dim);

    fused_kernel<<<batch / 64, 512, 0, stream>>>(x, cb, chalf, out, batch, dim, dim);
}

// Round 7
// 77.860 us; speedup vs baseline: 1.1679x; 1.1679x over previous
//
#include <hip/hip_runtime.h>
#include <math.h>

typedef __attribute__((ext_vector_type(8))) short short8;
typedef __attribute__((ext_vector_type(4))) float f32x4;

#define GLOBAL_AS __attribute__((address_space(1)))
#define LDS_AS __attribute__((address_space(3)))

__device__ inline short f2bf(float f) {
    unsigned u = __float_as_uint(f);
    u += 0x7FFFu + ((u >> 16) & 1u);   // RNE to bf16
    return (short)(u >> 16);
}

// ------ Kernel 1: cast centers (f32->bf16) + chalf[k] = 0.5*sum(c^2) in f32 ------
__global__ __launch_bounds__(256) void cast_centers_kernel(const float* __restrict__ c,
                                                           short* __restrict__ cb,
                                                           float* __restrict__ chalf, int dim) {
    int k = blockIdx.x;
    int t = threadIdx.x;
    const float* row = c + (size_t)k * dim;
    short* orow = cb + (size_t)k * dim;
    float s = 0.f;
    for (int i = t * 4; i < dim; i += blockDim.x * 4) {
        float4 v = *(const float4*)(row + i);
        s += v.x * v.x + v.y * v.y + v.z * v.z + v.w * v.w;
        short4 o;
        o.x = f2bf(v.x); o.y = f2bf(v.y); o.z = f2bf(v.z); o.w = f2bf(v.w);
        *(short4*)(orow + i) = o;
    }
#pragma unroll
    for (int off = 32; off; off >>= 1) s += __shfl_xor(s, off);
    __shared__ float red[4];
    if ((t & 63) == 0) red[t >> 6] = s;
    __syncthreads();
    if (t == 0) chalf[k] = 0.5f * (red[0] + red[1] + red[2] + red[3]);
}

// ------------- Kernel 2: fused GEMM (64 x FULL-ROW 1024) + log-softmax epilogue -------------
// logits[b,k] = x_b . c_k - 0.5*||c_k||^2  (row-constant -0.5*||x||^2 cancels in log_softmax)
// out[b,k] = logits[b,k] - logsumexp_k(logits[b,:])
//
// R3 structure + counted-vmcnt pipeline (T4): ring-2 B slots (64 KB each, all 1024 center
// rows x 32 K), ring-2 A slots (4 KB). Per unit, 2 phases each {8/4 ds_read_b128, issue
// 4 global_load_lds for unit u+1, barrier, setprio+16 MFMA, barrier}. The per-unit A f32
// prefetch is issued LAST (sched_barrier-pinned) so the unit-end wait is vmcnt(1) --
// staging drained, A prefetch stays in flight. Never drains to 0 until the tail.
// LDS rows are 64 B; 16B chunk h of row r stored at h ^ ((r>>1)&3): a wave64 b128 read
// covers all 32 banks evenly (free, verified vs R5's 8-way-conflict bug).
#define UK 32
#define BSL 65536
#define ABASE 131072   // 2 * BSL
#define SCR 139264     // ABASE + 2*4096

__global__ __launch_bounds__(512, 2) void fused_kernel(
    const float* __restrict__ x,     // [M][K] f32
    const short* __restrict__ cb,    // [N][K] bf16
    const float* __restrict__ chalf, // [N]
    float* __restrict__ out,         // [M][N]
    int M, int N, int K) {
    __shared__ char lds[143872];
    const int t = threadIdx.x;
    const int l = t & 63, w = t >> 6, lr = l & 15, hi = l >> 4;
    const int brow = blockIdx.x * 64;
    const size_t rowb = (size_t)K * 2;

    // ---- fragment-read offsets (swizzle chunk: hi ^ ((row>>1)&3); 64B LDS rows) ----
    const int sw = (hi ^ ((lr >> 1) & 3)) << 4;
    const int bfb = (w * 128 + lr) * 64 + sw;     // + n*1024 + (u&1)*BSL
    const int afb = ABASE + lr * 64 + sw;         // + m*1024 + (u&1)*4096

    // ---- A stage: thread t covers row t>>3, f32 cols (t&7)*4.. ----
    const int ar = t >> 3, ac = t & 7;
    const float* xsrc = x + (size_t)(brow + ar) * K + ac * 4;
    const int awofs = ABASE + ar * 64 + (((ac >> 1) ^ ((ar >> 1) & 3)) << 4) + (ac & 1) * 8;

    // ---- B stage: thread t, GLD j: center row j*128 + (t>>2), inverse-swizzled chunk ----
    const int Lg = (t & 3) ^ ((t >> 3) & 3);
    const char* bsrc = (const char*)cb + (size_t)(t >> 2) * rowb + Lg * 16;
    const size_t bjs = 128 * rowb;

#define GLD(gp, lo) __builtin_amdgcn_global_load_lds((const GLOBAL_AS int*)(gp), \
                        (LDS_AS int*)(lds + (lo)), 16, 0, 0)
#define STAGE4(uu, sl, j0) do {                                                 \
    _Pragma("unroll")                                                           \
    for (int j = (j0); j < (j0) + 4; ++j)                                       \
        GLD(bsrc + (size_t)j * bjs + (size_t)(uu) * 64, (sl)*BSL + j*8192 + t*16); \
    } while (0)
#define AWRITE(sl, fv) do {                                                     \
    short4 v_; v_.x = f2bf((fv).x); v_.y = f2bf((fv).y);                        \
    v_.z = f2bf((fv).z); v_.w = f2bf((fv).w);                                   \
    *(short4*)(lds + awofs + (sl)*4096) = v_; } while (0)

    f32x4 acc[4][8];
#pragma unroll
    for (int m = 0; m < 4; ++m)
#pragma unroll
        for (int n = 0; n < 8; ++n)
#pragma unroll
            for (int q = 0; q < 4; ++q) acc[m][n][q] = 0.f;

    const int nt = K / UK;                   // 32 units
    float4 faCur;
    {   // prologue: stage unit 0 (B 8 GLDs first, A-prefetch last -> vmcnt(1))
        float4 fa0 = *(const float4*)(xsrc);
        STAGE4(0, 0, 0); STAGE4(0, 0, 4);
        __builtin_amdgcn_sched_barrier(0);
        faCur = *(const float4*)(xsrc + UK);
        AWRITE(0, fa0);
        asm volatile("s_waitcnt vmcnt(1)" ::: "memory");
        asm volatile("s_waitcnt lgkmcnt(0)" ::: "memory");
    }
    __builtin_amdgcn_s_barrier();
    __builtin_amdgcn_sched_barrier(0);

    for (int u = 0; u < nt; ++u) {
        const char* Bb = lds + (u & 1) * BSL;
        const char* Ab = lds + (u & 1) * 4096;
        short8 af[4], bf0[4], bf1[4];
        // ================= phase 0: A + B(n0..3) reads, 4 GLDs, MFMA n0..3 =================
#pragma unroll
        for (int m = 0; m < 4; ++m) af[m] = *(const short8*)(Ab + afb + m * 1024);
#pragma unroll
        for (int n = 0; n < 4; ++n) bf0[n] = *(const short8*)(Bb + bfb + n * 1024);
        if (u <= 30) STAGE4(u + 1, (u + 1) & 1, 0);
        __builtin_amdgcn_sched_barrier(0);
        __builtin_amdgcn_s_barrier();
        __builtin_amdgcn_sched_barrier(0);
        __builtin_amdgcn_s_setprio(1);
#pragma unroll
        for (int m = 0; m < 4; ++m)
#pragma unroll
            for (int n = 0; n < 4; ++n)
                acc[m][n] = __builtin_amdgcn_mfma_f32_16x16x32_bf16(af[m], bf0[n], acc[m][n], 0, 0, 0);
        __builtin_amdgcn_s_setprio(0);
        __builtin_amdgcn_sched_barrier(0);
        __builtin_amdgcn_s_barrier();
        __builtin_amdgcn_sched_barrier(0);
        // ================= phase 1: B(n4..7) reads, 4 GLDs, A prefetch+write, MFMA n4..7 =====
#pragma unroll
        for (int n = 0; n < 4; ++n) bf1[n] = *(const short8*)(Bb + bfb + (n + 4) * 1024);
        if (u <= 30) STAGE4(u + 1, (u + 1) & 1, 4);
        __builtin_amdgcn_sched_barrier(0);      // pin: A prefetch issues AFTER the GLDs
        float4 faN = faCur;
        if (u <= 29) faN = *(const float4*)(xsrc + (size_t)(u + 2) * UK);
        if (u <= 30) AWRITE((u + 1) & 1, faCur);
        __builtin_amdgcn_sched_barrier(0);
        __builtin_amdgcn_s_barrier();
        __builtin_amdgcn_sched_barrier(0);
        __builtin_amdgcn_s_setprio(1);
#pragma unroll
        for (int m = 0; m < 4; ++m)
#pragma unroll
            for (int n = 0; n < 4; ++n)
                acc[m][n + 4] = __builtin_amdgcn_mfma_f32_16x16x32_bf16(af[m], bf1[n], acc[m][n + 4], 0, 0, 0);
        __builtin_amdgcn_s_setprio(0);
        if (u <= 29)      { asm volatile("s_waitcnt vmcnt(1)" ::: "memory"); }  // counted: A stays in flight
        else if (u == 30) { asm volatile("s_waitcnt vmcnt(0)" ::: "memory"); }  // tail drain
        asm volatile("s_waitcnt lgkmcnt(0)" ::: "memory");                       // A ds_write visible
        __builtin_amdgcn_sched_barrier(0);
        __builtin_amdgcn_s_barrier();
        __builtin_amdgcn_sched_barrier(0);
        faCur = faN;
    }

    // ================= fused log-softmax epilogue =================
    // C/D frag layout: col = lane&15, row = (lane>>4)*4 + q.
    // Lane holds rows R = m*16 + hi*4 + q, cols w*128 + n*16 + lr.
    float ch[8];
#pragma unroll
    for (int n = 0; n < 8; ++n) ch[n] = chalf[w * 128 + n * 16 + lr];

    // pass 1: per-lane max over n, reduce over lr-lanes, cross-wave via LDS scratch
    float pm[4][4];
#pragma unroll
    for (int m = 0; m < 4; ++m)
#pragma unroll
        for (int q = 0; q < 4; ++q) {
            float v = acc[m][0][q] - ch[0];
#pragma unroll
            for (int n = 1; n < 8; ++n) v = fmaxf(v, acc[m][n][q] - ch[n]);
            pm[m][q] = v;
        }
#pragma unroll
    for (int d = 1; d <= 8; d <<= 1)
#pragma unroll
        for (int m = 0; m < 4; ++m)
#pragma unroll
            for (int q = 0; q < 4; ++q) pm[m][q] = fmaxf(pm[m][q], __shfl_xor(pm[m][q], d));
    if (lr == 0) {
#pragma unroll
        for (int m = 0; m < 4; ++m)
#pragma unroll
            for (int q = 0; q < 4; ++q)
                *(float*)(lds + SCR + (m * 16 + hi * 4 + q) * 32 + w * 4) = pm[m][q]; // wmax[R][w]
    }
    __syncthreads();
    if (t < 64) {
        float4 a = *(const float4*)(lds + SCR + t * 32);
        float4 b = *(const float4*)(lds + SCR + t * 32 + 16);
        float g = fmaxf(fmaxf(fmaxf(a.x, a.y), fmaxf(a.z, a.w)),
                        fmaxf(fmaxf(b.x, b.y), fmaxf(b.z, b.w)));
        *(float*)(lds + SCR + 4096 + t * 4) = g;                                      // gmax[R]
    }
    __syncthreads();

    // pass 2: sum of exp
    float ps[4][4];
#pragma unroll
    for (int m = 0; m < 4; ++m)
#pragma unroll
        for (int q = 0; q < 4; ++q) {
            const float g = *(const float*)(lds + SCR + 4096 + (m * 16 + hi * 4 + q) * 4);
            float s = 0.f;
#pragma unroll
            for (int n = 0; n < 8; ++n) s += __expf(acc[m][n][q] - ch[n] - g);
            ps[m][q] = s;
        }
#pragma unroll
    for (int d = 1; d <= 8; d <<= 1)
#pragma unroll
        for (int m = 0; m < 4; ++m)
#pragma unroll
            for (int q = 0; q < 4; ++q) ps[m][q] += __shfl_xor(ps[m][q], d);
    if (lr == 0) {
#pragma unroll
        for (int m = 0; m < 4; ++m)
#pragma unroll
            for (int q = 0; q < 4; ++q)
                *(float*)(lds + SCR + 2048 + (m * 16 + hi * 4 + q) * 32 + w * 4) = ps[m][q]; // wsum[R][w]
    }
    __syncthreads();
    if (t < 64) {
        float4 a = *(const float4*)(lds + SCR + 2048 + t * 32);
        float4 b = *(const float4*)(lds + SCR + 2048 + t * 32 + 16);
        float s = (a.x + a.y + a.z + a.w) + (b.x + b.y + b.z + b.w);
        *(float*)(lds + SCR + 4352 + t * 4) =
            *(const float*)(lds + SCR + 4096 + t * 4) + __logf(s);                    // lse[R]
    }
    __syncthreads();

    // write final output
#pragma unroll
    for (int m = 0; m < 4; ++m)
#pragma unroll
        for (int q = 0; q < 4; ++q) {
            const int R = m * 16 + hi * 4 + q;
            const float lse = *(const float*)(lds + SCR + 4352 + R * 4);
            float* orow = out + (size_t)(brow + R) * N + w * 128 + lr;
#pragma unroll
            for (int n = 0; n < 8; ++n)
                orow[n * 16] = acc[m][n][q] - ch[n] - lse;
        }
#undef STAGE4
#undef AWRITE
#undef GLD
}

extern "C" void kernel_launch(void* const* d_in, const int* in_sizes, int n_in,
                              void* d_out, int out_size, void* d_ws, size_t ws_size,
                              hipStream_t stream) {
    const float* x = (const float*)d_in[0];
    const float* c = (const float*)d_in[1];
    float* out = (float*)d_out;

    int dim = (int)(sqrt((double)in_sizes[1]) + 0.5);   // 1024
    int batch = in_sizes[0] / dim;                      // 16384

    // workspace layout: [centers bf16][chalf f32]
    size_t cb_bytes = (size_t)dim * dim * 2;
    short* cb = (short*)d_ws;
    float* chalf = (float*)((char*)d_ws + cb_bytes);

    cast_centers_kernel<<<dim, 256, 0, stream>>>(c, cb, chalf, dim);

    fused_kernel<<<batch / 64, 512, 0, stream>>>(x, cb, chalf, out, batch, dim, dim);
}